// Round 11
// baseline (468.477 us; speedup 1.0000x reference)
//
#include <hip/hip_runtime.h>

typedef unsigned short u16;
typedef __attribute__((ext_vector_type(8))) unsigned short u16x8;
typedef __attribute__((ext_vector_type(4))) unsigned short u16x4;
typedef __attribute__((ext_vector_type(4))) float f32x4;

#define DEVI __device__ __forceinline__

// ---------------- helpers ----------------
DEVI u16 f2bf(float f){
  unsigned u = __float_as_uint(f);
  u += 0x7FFFu + ((u >> 16) & 1u);      // round-to-nearest-even
  return (u16)(u >> 16);
}

DEVI float bf2f(u16 b){
  return __uint_as_float((unsigned)b << 16);
}

DEVI void gload16(const void* g, void* l){
  __builtin_amdgcn_global_load_lds((const __attribute__((address_space(1))) void*)g,
                                   (__attribute__((address_space(3))) void*)l, 16, 0, 0);
}

DEVI float wave_sum(float v){
#pragma unroll
  for (int o = 32; o; o >>= 1) v += __shfl_xor(v, o, 64);
  return v;
}

#define MFMA16(a,b,c) __builtin_amdgcn_mfma_f32_16x16x32_bf16((a),(b),(c),0,0,0)

// ---------------- prep: Wq/Wv transposes + enc convert + qsbias --------------
// flat grid: [0,1024) Wq  [1024,2048) Wv  [2048,3072) enc  [3072,5120) qsbias
__global__ __launch_bounds__(256) void prep_k(
    const float* __restrict__ Wq, const float* __restrict__ Wv,
    const float* __restrict__ enc, const float* __restrict__ dist,
    const float* __restrict__ Wth0, const float* __restrict__ bth0,
    const float* __restrict__ Wto0, const float* __restrict__ bto0,
    u16* __restrict__ Wqt, u16* __restrict__ Wvt,
    u16* __restrict__ encb, u16* __restrict__ qs0){
  __shared__ float tile[64][65];
  const int t = blockIdx.x;
  if (t < 2048){                          // Wq / Wv 64x64 transpose tiles
    const int sel = t >> 10, ti2 = t & 1023, mat = ti2 >> 8, ti = ti2 & 255;
    const float* in = (sel ? Wv : Wq) + (size_t)mat * 1048576;
    u16* out = (sel ? Wvt : Wqt) + (size_t)mat * 1048576;
    const int r0 = (ti & 15) << 6, c0 = (ti >> 4) << 6;
    const int rr0 = threadIdx.x >> 4, cc = (threadIdx.x & 15) * 4;
#pragma unroll
    for (int it = 0; it < 4; it++){
      const int rr = rr0 + it * 16;
      const float4 v = *(const float4*)(in + (size_t)(r0 + rr) * 1024 + c0 + cc);
      tile[rr][cc] = v.x; tile[rr][cc+1] = v.y;
      tile[rr][cc+2] = v.z; tile[rr][cc+3] = v.w;
    }
    __syncthreads();
#pragma unroll
    for (int it = 0; it < 2; it++){
      const int chunk = threadIdx.x + it * 256;
      const int c = chunk >> 3, q = (chunk & 7) * 8;
      union { u16x8 v8; u16 e[8]; } ob;
#pragma unroll
      for (int i = 0; i < 8; i++) ob.e[i] = f2bf(tile[q + i][c]);
      *(u16x8*)(out + (size_t)(c0 + c) * 1024 + r0 + q) = ob.v8;
    }
  } else if (t < 3072){                   // enc f32 -> bf16
    const int i = (t - 2048) * 256 + threadIdx.x;
    float4 v = ((const float4*)enc)[i];
    u16x4 o = { f2bf(v.x), f2bf(v.y), f2bf(v.z), f2bf(v.w) };
    ((u16x4*)encb)[i] = o;
  } else {                                // qsbias -> bf16
    const int bi = t - 3072, ly = bi >> 9, xi = bi & 511;
    const float* Wth = Wth0 + ly*32;
    const float* bth = bth0 + ly*32;
    const float* Wto = Wto0 + ly*32;
    u16* qs = qs0 + (size_t)ly * 524288;
    const int idx = xi * 256 + threadIdx.x;
    float4 s4 = ((const float4*)dist)[idx];
    float sv[4] = { s4.x, s4.y, s4.z, s4.w };
    float r[4];
    const float b0 = bto0[ly];
#pragma unroll
    for (int c = 0; c < 4; c++) r[c] = b0;
#pragma unroll
    for (int k = 0; k < 32; k++){
      const float wk = Wth[k], bk = bth[k], ok = Wto[k];
#pragma unroll
      for (int c = 0; c < 4; c++){
        float h = fmaxf(sv[c] * wk + bk, 0.0f);
        r[c] += h * ok;
      }
    }
    u16x4 o = { f2bf(r[0]), f2bf(r[1]), f2bf(r[2]), f2bf(r[3]) };
    ((u16x4*)qs)[idx] = o;
  }
}

// ---------------- layernorm: rows of 1024, (x-m)/(std+eps), bf16 out ----------
template<int COPY>
__global__ __launch_bounds__(256) void layernorm_k(const float* __restrict__ in,
                                                   float* __restrict__ x,
                                                   u16* __restrict__ outp){
  const int row = blockIdx.x;
  const int tid = threadIdx.x;
  const float4 v = ((const float4*)(in + (size_t)row * 1024))[tid];
  if (COPY) ((float4*)x)[(size_t)row * 256 + tid] = v;
  __shared__ float sb[8];
  const int wid = tid >> 6, lane = tid & 63;
  float s = wave_sum(v.x + v.y + v.z + v.w);
  if (lane == 0) sb[wid] = s;
  __syncthreads();
  const float mean = (sb[0] + sb[1] + sb[2] + sb[3]) * (1.0f / 1024.0f);
  const float dx = v.x - mean, dy = v.y - mean, dz = v.z - mean, dw = v.w - mean;
  float q = wave_sum(dx*dx + dy*dy + dz*dz + dw*dw);
  if (lane == 0) sb[4 + wid] = q;
  __syncthreads();
  const float sd = sqrtf((sb[4] + sb[5] + sb[6] + sb[7]) * (1.0f / 1024.0f));
  const float inv = 1.0f / (sd + 1e-6f);
  u16x4 o = { f2bf(dx*inv), f2bf(dy*inv), f2bf(dz*inv), f2bf(dw*inv) };
  ((u16x4*)outp)[(size_t)row * 256 + tid] = o;
}

// ---------------- 128x64 GEMM, B reg-staged from NATURAL-layout f32 weight ---
// C[M][Nd] = A[M][Krange] @ W[Krange][col0..col0+64).  A: bf16 gload_lds
// (T2-swizzled).  B: lane = n-column (64 lanes = 64 rows), wave w = k-chunk
// pair {w*2, w*2+1}; 16 coalesced f32 loads/lane (256B/instr), cvt, 2x
// ds_write_b128 at swizzled slot (chunk^(lane&7)) — same pattern as the
// proven read side, no bank pathology.  T14: loads before MFMA, writes after.
// MODE 0: bf16   3: bf16 relu(+bias)   5: f32 partial
template<int MODE>
DEVI void gemmw_core(const u16* A, int lda, const float* W, int ldw,
                     int kbase, int Klen, int Nd, void* Cout,
                     const float* bias, u16* Als, u16* Bls, int row0, int col0){
  const int tid = threadIdx.x;
  const int wid = tid >> 6, lane = tid & 63;
  const int wm = wid >> 1, wn = wid & 1;
  const int lrow = lane & 15, g = lane >> 4, e7 = lane & 7;
  f32x4 acc[4][2] = {};

  const int scol = ((lane & 7) ^ ((lane >> 3) & 7)) * 8;
  const u16* Ag = A + (size_t)(row0 + wid*8 + (lane >> 3)) * lda + scol;
  const int dst0 = wid * 512;

  const float* Wg = W + (size_t)(kbase + wid*16) * ldw + col0 + lane;
  const int brow = lane * 64;
  const int sl0 = ((wid*2    ) ^ (lane & 7)) * 8;
  const int sl1 = ((wid*2 + 1) ^ (lane & 7)) * 8;

  const int nt = Klen >> 6;
  float wv[16];

#define LOADW(k0)                                                   \
  { _Pragma("unroll")                                               \
    for (int i = 0; i < 16; i++)                                    \
      wv[i] = Wg[(size_t)((k0) + i) * ldw]; }

#define WRITEW(buf)                                                 \
  { union { u16x8 v8; u16 e[8]; } o0, o1;                           \
    _Pragma("unroll")                                               \
    for (int i = 0; i < 8; i++){ o0.e[i] = f2bf(wv[i]); o1.e[i] = f2bf(wv[8+i]); } \
    *(u16x8*)(Bls + (buf)*4096 + brow + sl0) = o0.v8;               \
    *(u16x8*)(Bls + (buf)*4096 + brow + sl1) = o1.v8; }

#define STAGEA(buf, k0)                                             \
  { _Pragma("unroll")                                               \
    for (int q = 0; q < 4; q++)                                     \
      gload16(Ag + (size_t)q*32*lda + (k0), Als + (buf)*8192 + dst0 + q*2048); }

  STAGEA(0, 0); LOADW(0); WRITEW(0);
  __syncthreads();

  for (int t = 0; t < nt; t++){
    const int cur = t & 1;
    if (t + 1 < nt){ STAGEA(cur ^ 1, (t + 1) << 6); LOADW((t + 1) << 6); }
    const u16* Ab = Als + cur * 8192;
    const u16* Bb = Bls + cur * 4096;
#pragma unroll
    for (int ks = 0; ks < 2; ks++){
      const int sl = (((ks << 2) + g) ^ e7) << 3;
      u16x8 av[4], bv[2];
#pragma unroll
      for (int mi = 0; mi < 4; mi++)
        av[mi] = *(const u16x8*)(Ab + (wm*64 + mi*16 + lrow) * 64 + sl);
#pragma unroll
      for (int ni = 0; ni < 2; ni++)
        bv[ni] = *(const u16x8*)(Bb + (wn*32 + ni*16 + lrow) * 64 + sl);
#pragma unroll
      for (int mi = 0; mi < 4; mi++)
#pragma unroll
        for (int ni = 0; ni < 2; ni++)
          acc[mi][ni] = MFMA16(av[mi], bv[ni], acc[mi][ni]);
    }
    if (t + 1 < nt) WRITEW(cur ^ 1);     // vmcnt wait lands here, after MFMA
    __syncthreads();
  }
#undef LOADW
#undef WRITEW
#undef STAGEA

#pragma unroll
  for (int mi = 0; mi < 4; mi++){
#pragma unroll
    for (int ni = 0; ni < 2; ni++){
      const int col = col0 + wn*32 + ni*16 + lrow;
#pragma unroll
      for (int j = 0; j < 4; j++){
        const int row = row0 + wm*64 + mi*16 + g*4 + j;
        float v = acc[mi][ni][j];
        if (MODE == 3) v = fmaxf(v + bias[col], 0.0f);
        if (MODE == 0 || MODE == 3)
          ((u16*)Cout)[(size_t)row * Nd + col] = f2bf(v);
        else
          ((float*)Cout)[(size_t)row * Nd + col] = v;
      }
    }
  }
}

template<int MODE>
__global__ __launch_bounds__(256) void gemmw_k(const u16* __restrict__ A, int lda,
    const float* __restrict__ W, int ldw, int Klen, int Nd, void* __restrict__ Cout,
    const float* __restrict__ bias){
  __shared__ __align__(16) u16 Als[2 * 8192];
  __shared__ __align__(16) u16 Bls[2 * 4096];
  gemmw_core<MODE>(A, lda, W, ldw, 0, Klen, Nd, Cout, bias,
                   Als, Bls, blockIdx.y * 128, blockIdx.x * 64);
}

// split-K=4 into f32 partials (Nd=1024)
__global__ __launch_bounds__(256) void gemmw_splitk_k(const u16* __restrict__ A, int lda,
    const float* __restrict__ W, int ldw, int Klen, float* __restrict__ part){
  __shared__ __align__(16) u16 Als[2 * 8192];
  __shared__ __align__(16) u16 Bls[2 * 4096];
  const int z = blockIdx.z;
  gemmw_core<5>(A + (size_t)z * Klen, lda, W, ldw, z * Klen, Klen, 1024,
                part + (size_t)z * 1048576, nullptr,
                Als, Bls, blockIdx.y * 128, blockIdx.x * 64);
}

// ---------------- bf16xbf16 core (kept for the V^T scatter GEMM) ------------
template<int MODE, int BN>
DEVI void gemm128_core(const u16* A, int lda, const u16* Bt, int ldb,
                       int Klen, int Nd, void* Cout,
                       u16* Als, u16* Bls, int row0, int col0){
  constexpr int WN = BN / 2, FN = BN / 32;
  constexpr int BSZ = BN * 64;
  const int tid = threadIdx.x;
  const int wid = tid >> 6, lane = tid & 63;
  const int wm = wid >> 1, wn = wid & 1;
  const int lrow = lane & 15, g = lane >> 4, e7 = lane & 7;
  f32x4 acc[4][FN] = {};

  const int scol = ((lane & 7) ^ ((lane >> 3) & 7)) * 8;
  const u16* Ag = A + (size_t)(row0 + wid*8 + (lane >> 3)) * lda + scol;
  const u16* Bg = Bt + (size_t)(col0 + wid*8 + (lane >> 3)) * ldb + scol;
  const int dst0 = wid * 512;
  const int nt = Klen >> 6;

#define STAGE128(buf, k0)                                                     \
  {                                                                           \
    _Pragma("unroll")                                                         \
    for (int q = 0; q < 4; q++)                                               \
      gload16(Ag + (size_t)q*32*lda + (k0), Als + (buf)*8192 + dst0 + q*2048);\
    _Pragma("unroll")                                                         \
    for (int q = 0; q < BN/32; q++)                                           \
      gload16(Bg + (size_t)q*32*ldb + (k0), Bls + (buf)*BSZ + dst0 + q*2048); \
  }

  STAGE128(0, 0);
  __syncthreads();

  for (int t = 0; t < nt; t++){
    const int cur = t & 1;
    if (t + 1 < nt) STAGE128(cur ^ 1, (t + 1) << 6);
    const u16* Ab = Als + cur * 8192;
    const u16* Bb = Bls + cur * BSZ;
#pragma unroll
    for (int ks = 0; ks < 2; ks++){
      const int sl = (((ks << 2) + g) ^ e7) << 3;
      u16x8 av[4], bv[FN];
#pragma unroll
      for (int mi = 0; mi < 4; mi++)
        av[mi] = *(const u16x8*)(Ab + (wm*64 + mi*16 + lrow) * 64 + sl);
#pragma unroll
      for (int ni = 0; ni < FN; ni++)
        bv[ni] = *(const u16x8*)(Bb + (wn*WN + ni*16 + lrow) * 64 + sl);
#pragma unroll
      for (int mi = 0; mi < 4; mi++)
#pragma unroll
        for (int ni = 0; ni < FN; ni++)
          acc[mi][ni] = MFMA16(av[mi], bv[ni], acc[mi][ni]);
    }
    __syncthreads();
  }
#undef STAGE128

#pragma unroll
  for (int mi = 0; mi < 4; mi++){
#pragma unroll
    for (int ni = 0; ni < FN; ni++){
      const int col = col0 + wn*WN + ni*16 + lrow;
#pragma unroll
      for (int j = 0; j < 4; j++){
        const int row = row0 + wm*64 + mi*16 + g*4 + j;
        float v = acc[mi][ni][j];
        if (MODE == 6)
          ((u16*)Cout)[(size_t)((col >> 9)*16 + (row >> 6)) * 32768
                       + (row & 63) * 512 + (col & 511)] = f2bf(v);
        else
          ((u16*)Cout)[(size_t)row * Nd + col] = f2bf(v);
      }
    }
  }
}

// K-proj (weight-direct f32) + V-proj (transposed output) for ALL layers
__global__ __launch_bounds__(256) void gemmKV_k(const u16* __restrict__ encb,
    const float* __restrict__ Wk, const u16* __restrict__ Wvt,
    u16* __restrict__ Kb, u16* __restrict__ Vt){
  __shared__ __align__(16) u16 Als[2 * 8192];
  __shared__ __align__(16) u16 Bls[2 * 4096];
  const int z = blockIdx.z, l = z >> 1;
  if ((z & 1) == 0)
    gemmw_core<0>(encb, 1024, Wk + (size_t)l*1048576, 1024, 0, 1024, 1024,
                  Kb + (size_t)l*1048576, nullptr,
                  Als, Bls, blockIdx.y * 128, blockIdx.x * 64);
  else   // C[h'][b*512+t] = Wvt @ encb^T, scattered into Vt[(b,n,h),t]
    gemm128_core<6, 64>(Wvt + (size_t)l*1048576, 1024, encb, 1024, 1024, 1024,
                        Vt + (size_t)l*1048576,
                        Als, Bls, blockIdx.y * 128, blockIdx.x * 64);
}

// ---------------- reduce + layernorm ----------------
template<int BIAS, int LAST>
__global__ __launch_bounds__(256) void reduce_ln_k(const float* __restrict__ part,
    const float* __restrict__ bias, float* __restrict__ x, u16* __restrict__ xn,
    float* __restrict__ dout){
  const int row = blockIdx.x, tid = threadIdx.x;
  const size_t idx = (size_t)row * 256 + tid;
  float4 v = ((const float4*)x)[idx];
  float4 p0 = ((const float4*)part)[idx];
  float4 p1 = ((const float4*)(part + 1048576))[idx];
  float4 p2 = ((const float4*)(part + 2097152))[idx];
  float4 p3 = ((const float4*)(part + 3145728))[idx];
  v.x += p0.x + p1.x + p2.x + p3.x;
  v.y += p0.y + p1.y + p2.y + p3.y;
  v.z += p0.z + p1.z + p2.z + p3.z;
  v.w += p0.w + p1.w + p2.w + p3.w;
  if (BIAS){
    const float4 b = *(const float4*)(bias + tid * 4);
    v.x += b.x; v.y += b.y; v.z += b.z; v.w += b.w;
  }
  if (!LAST) ((float4*)x)[idx] = v;

  __shared__ float sb[8];
  const int wid = tid >> 6, lane = tid & 63;
  float s = wave_sum(v.x + v.y + v.z + v.w);
  if (lane == 0) sb[wid] = s;
  __syncthreads();
  const float mean = (sb[0] + sb[1] + sb[2] + sb[3]) * (1.0f / 1024.0f);
  const float dx = v.x - mean, dy = v.y - mean, dz = v.z - mean, dw = v.w - mean;
  float q = wave_sum(dx*dx + dy*dy + dz*dz + dw*dw);
  if (lane == 0) sb[4 + wid] = q;
  __syncthreads();
  const float sd = sqrtf((sb[4] + sb[5] + sb[6] + sb[7]) * (1.0f / 1024.0f));
  const float inv = 1.0f / (sd + 1e-6f);
  if (LAST){
    ((float4*)dout)[idx] = make_float4(dx*inv, dy*inv, dz*inv, dw*inv);
  } else {
    u16x4 o = { f2bf(dx*inv), f2bf(dy*inv), f2bf(dz*inv), f2bf(dw*inv) };
    ((u16x4*)xn)[idx] = o;
  }
}

// ---------------- fused flash attention (Q-projection fused in) -------------
// grid (n=16, ftile=8, b=2); 4 waves, wave w owns 16 q-rows. 2 blocks/CU.
__global__ __launch_bounds__(256, 2) void attn_k(const u16* __restrict__ xn,
    const u16* __restrict__ Wqt,
    const u16* __restrict__ Kb, const u16* __restrict__ Vt,
    const u16* __restrict__ qs, const float* __restrict__ abias,
    u16* __restrict__ aout){
  const int n = blockIdx.x, f0 = blockIdx.y * 64, b = blockIdx.z;
  const int w = threadIdx.x >> 6, lane = threadIdx.x & 63;
  const int l15 = lane & 15, g = lane >> 4, e7 = lane & 7;
  const int fw = f0 + w * 16;
  __shared__ __align__(16) u16 Pl[4][16 * 512];   // 64 KB
  u16* pw = &Pl[w][0];

  u16x8 qf0, qf1;
  {
    u16* Als = &Pl[0][0];
    u16* Bls = &Pl[1][0];
    const int wm = w >> 1, wn = w & 1;
    f32x4 qac[2][2] = {};
    const int scol = ((lane & 7) ^ ((lane >> 3) & 7)) * 8;
    const u16* Ag = xn + (size_t)(b*512 + f0 + w*8 + (lane >> 3)) * 1024 + scol;
    const u16* Bg = Wqt + (size_t)(n*64 + w*8 + (lane >> 3)) * 1024 + scol;
    const int dq = w * 512;

#define STAGEQ(buf, k0)                                         \
    gload16(Ag + (k0),            Als + (buf)*4096 + dq);       \
    gload16(Ag + 32*1024 + (k0),  Als + (buf)*4096 + dq + 2048);\
    gload16(Bg + (k0),            Bls + (buf)*4096 + dq);       \
    gload16(Bg + 32*1024 + (k0),  Bls + (buf)*4096 + dq + 2048);

    STAGEQ(0, 0);
    __syncthreads();
    for (int t = 0; t < 16; t++){
      const int cur = t & 1;
      if (t < 15){ STAGEQ(cur ^ 1, (t + 1) << 6); }
      const u16* Ab = Als + cur * 4096;
      const u16* Bb = Bls + cur * 4096;
#pragma unroll
      for (int ks = 0; ks < 2; ks++){
        const int sl = (((ks << 2) + g) ^ e7) << 3;
        u16x8 av[2], bv[2];
#pragma unroll
        for (int mi = 0; mi < 2; mi++)
          av[mi] = *(const u16x8*)(Ab + (wm*32 + mi*16 + l15) * 64 + sl);
#pragma unroll
        for (int ni = 0; ni < 2; ni++)
          bv[ni] = *(const u16x8*)(Bb + (wn*32 + ni*16 + l15) * 64 + sl);
#pragma unroll
        for (int mi = 0; mi < 2; mi++)
#pragma unroll
          for (int ni = 0; ni < 2; ni++)
            qac[mi][ni] = MFMA16(av[mi], bv[ni], qac[mi][ni]);
      }
      __syncthreads();
    }
#undef STAGEQ

    u16* Qt = &Pl[2][0];
#pragma unroll
    for (int mi = 0; mi < 2; mi++)
#pragma unroll
      for (int ni = 0; ni < 2; ni++)
#pragma unroll
        for (int j = 0; j < 4; j++){
          const int r = wm*32 + mi*16 + g*4 + j;
          const int c = wn*32 + ni*16 + l15;
          const int byte = r*128 + (((c >> 3) ^ (r & 7)) << 4) + (c & 7)*2;
          *(u16*)((char*)Qt + byte) = f2bf(qac[mi][ni][j] * 0.125f);
        }
    __syncthreads();
    const int r = w*16 + l15;
    const char* qrow = (char*)Qt + r*128;
    qf0 = *(const u16x8*)(qrow + ((g ^ (r & 7)) << 4));
    qf1 = *(const u16x8*)(qrow + (((4 + g) ^ (r & 7)) << 4));
    __syncthreads();
  }

  // QK^T: acc[tf] holds S[fw+l15][tf*16 + g*4 + j]
  f32x4 acc[32];
  const u16* kp = Kb + ((size_t)b*512 + l15) * 1024 + n*64 + g*8;
#pragma unroll
  for (int tf = 0; tf < 32; tf++){
    u16x8 k0 = *(const u16x8*)(kp + (size_t)tf*16*1024);
    u16x8 k1 = *(const u16x8*)(kp + (size_t)tf*16*1024 + 32);
    f32x4 z = {0.f, 0.f, 0.f, 0.f};
    z = MFMA16(k0, qf0, z);
    acc[tf] = MFMA16(k1, qf1, z);
  }

  // + qs bias (bf16) + attn bias, row max
  const u16* qsp = qs + ((size_t)b*512 + fw + l15) * 512 + g*4;
  const float* abp = abias + (size_t)b*512 + g*4;
  float m = -3.0e38f;
#pragma unroll
  for (int tf = 0; tf < 32; tf++){
    u16x4 qv = *(const u16x4*)(qsp + tf*16);
    float4 av = *(const float4*)(abp + tf*16);
    acc[tf][0] += bf2f(qv[0]) + av.x;
    acc[tf][1] += bf2f(qv[1]) + av.y;
    acc[tf][2] += bf2f(qv[2]) + av.z;
    acc[tf][3] += bf2f(qv[3]) + av.w;
    m = fmaxf(m, fmaxf(fmaxf(acc[tf][0], acc[tf][1]), fmaxf(acc[tf][2], acc[tf][3])));
  }
  m = fmaxf(m, __shfl_xor(m, 16, 64));
  m = fmaxf(m, __shfl_xor(m, 32, 64));

  float s = 0.f;
#pragma unroll
  for (int tf = 0; tf < 32; tf++){
#pragma unroll
    for (int j = 0; j < 4; j++){
      float e = __expf(acc[tf][j] - m);
      acc[tf][j] = e; s += e;
    }
  }
  s += __shfl_xor(s, 16, 64);
  s += __shfl_xor(s, 32, 64);
  const float inv = 1.0f / s;
  float invj[4];
#pragma unroll
  for (int j = 0; j < 4; j++) invj[j] = __shfl(inv, g*4 + j, 64);

  // store unnormalized P (<=1) row-major [16][512] bf16, chunk-swizzled
#pragma unroll
  for (int tf = 0; tf < 32; tf++){
    const int chunk = tf*2 + (g >> 1);
    const int boff = (l15 << 10) + ((chunk ^ e7) << 4) + ((g & 1) << 3);
    u16x4 pk = { f2bf(acc[tf][0]), f2bf(acc[tf][1]), f2bf(acc[tf][2]), f2bf(acc[tf][3]) };
    *(u16x4*)((char*)pw + boff) = pk;
  }

  // PV: O[f][h] = P[f][:] @ V[:][h];  V^T frags direct from global (L2-resident)
  f32x4 oacc[4] = {};
  const u16* vp = Vt + ((size_t)(b*16 + n)*64 + l15) * 512 + g*8;
  for (int kk = 0; kk < 16; kk++){
    u16x8 pa = *(const u16x8*)((char*)pw + (l15 << 10) + ((((kk << 2) + g) ^ e7) << 4));
#pragma unroll
    for (int nf = 0; nf < 4; nf++){
      u16x8 vb = *(const u16x8*)(vp + (size_t)nf*16*512 + kk*32);
      oacc[nf] = MFMA16(pa, vb, oacc[nf]);
    }
  }

  u16* op = aout + ((size_t)b*512 + fw + g*4) * 1024 + n*64 + l15;
#pragma unroll
  for (int nf = 0; nf < 4; nf++)
#pragma unroll
    for (int j = 0; j < 4; j++)
      op[(size_t)j*1024 + nf*16] = f2bf(oacc[nf][j] * invj[j]);
}

// ---------------- host ----------------
extern "C" void kernel_launch(void* const* d_in, const int* in_sizes, int n_in,
                              void* d_out, int out_size, void* d_ws, size_t ws_size,
                              hipStream_t stream){
  const float* dec_in   = (const float*)d_in[0];
  const float* enc      = (const float*)d_in[1];
  const float* dist     = (const float*)d_in[3];
  const float* abias    = (const float*)d_in[5];
  const float* Wq  = (const float*)d_in[6];
  const float* Wk  = (const float*)d_in[7];
  const float* Wv  = (const float*)d_in[8];
  const float* Wo  = (const float*)d_in[9];
  const float* Wth = (const float*)d_in[10];
  const float* bth = (const float*)d_in[11];
  const float* Wto = (const float*)d_in[12];
  const float* bto = (const float*)d_in[13];
  const float* Wf1 = (const float*)d_in[14];
  const float* bf1 = (const float*)d_in[15];
  const float* Wf2 = (const float*)d_in[16];
  const float* bf2 = (const float*)d_in[17];
  float* dout = (float*)d_out;

  char* wp = (char*)d_ws;
  auto alloc = [&](size_t n) -> char* {
    char* p = wp; wp += (n + 255) & ~(size_t)255; return p;
  };
  float* x     = (float*)alloc((size_t)1048576 * 4);
  u16*  xn     = (u16*)alloc((size_t)1048576 * 2);
  u16*  encb   = (u16*)alloc((size_t)1048576 * 2);
  u16*  Wqt    = (u16*)alloc((size_t)4194304 * 2);    // 4 layers
  u16*  Wvt    = (u16*)alloc((size_t)4194304 * 2);
  u16*  Kb     = (u16*)alloc((size_t)4194304 * 2);    // 4 layers
  u16*  Vt     = (u16*)alloc((size_t)4194304 * 2);
  u16*  qs     = (u16*)alloc((size_t)2097152 * 2);    // 4 layers, bf16
  u16*  aout   = (u16*)alloc((size_t)1048576 * 2);
  u16*  ffh    = (u16*)alloc((size_t)4194304 * 2);
  float* part  = (float*)alloc((size_t)4194304 * 4);  // 4x 1024x1024 f32

  // ---- upfront (3 dispatches) ----
  prep_k<<<5120, 256, 0, stream>>>(Wq, Wv, enc, dist, Wth, bth, Wto, bto,
                                   Wqt, Wvt, encb, qs);
  gemmKV_k<<<dim3(16, 8, 8), 256, 0, stream>>>(encb, Wk, Wvt, Kb, Vt);
  layernorm_k<1><<<1024, 256, 0, stream>>>(dec_in, x, xn);

  // ---- per-layer serial chain: 6 dispatches ----
  for (int i = 0; i < 4; i++){
    const size_t wo = (size_t)i * 1048576;

    // fused attention (Q-proj + logits + biases + softmax + PV)
    attn_k<<<dim3(16, 8, 2), 256, 0, stream>>>(xn, Wqt + wo, Kb + wo, Vt + wo,
                                               qs + (size_t)i * 524288, abias, aout);

    // O projection (split-K=4, weight-direct) + fused residual+LN
    gemmw_splitk_k<<<dim3(16, 8, 4), 256, 0, stream>>>(aout, 1024, Wo + wo, 1024, 256, part);
    reduce_ln_k<0, 0><<<1024, 256, 0, stream>>>(part, nullptr, x, xn, nullptr);

    // FFN (weight-direct)
    gemmw_k<3><<<dim3(64, 8), 256, 0, stream>>>(xn, 1024, Wf1 + (size_t)i*4194304, 4096,
                                                1024, 4096, ffh, bf1 + (size_t)i*4096);
    gemmw_splitk_k<<<dim3(16, 8, 4), 256, 0, stream>>>(ffh, 4096, Wf2 + (size_t)i*4194304, 1024,
                                                       1024, part);
    if (i < 3)
      reduce_ln_k<1, 0><<<1024, 256, 0, stream>>>(part, bf2 + (size_t)i*1024, x, xn, nullptr);
    else
      reduce_ln_k<1, 1><<<1024, 256, 0, stream>>>(part, bf2 + (size_t)i*1024, x, nullptr, dout);
  }
}

// Round 12
// 445.401 us; speedup vs baseline: 1.0518x; 1.0518x over previous
//
#include <hip/hip_runtime.h>

typedef unsigned short u16;
typedef __attribute__((ext_vector_type(8))) unsigned short u16x8;
typedef __attribute__((ext_vector_type(4))) unsigned short u16x4;
typedef __attribute__((ext_vector_type(4))) float f32x4;

#define DEVI __device__ __forceinline__

// ---------------- helpers ----------------
DEVI u16 f2bf(float f){
  unsigned u = __float_as_uint(f);
  u += 0x7FFFu + ((u >> 16) & 1u);      // round-to-nearest-even
  return (u16)(u >> 16);
}

DEVI float bf2f(u16 b){
  return __uint_as_float((unsigned)b << 16);
}

DEVI void gload16(const void* g, void* l){
  __builtin_amdgcn_global_load_lds((const __attribute__((address_space(1))) void*)g,
                                   (__attribute__((address_space(3))) void*)l, 16, 0, 0);
}

DEVI float wave_sum(float v){
#pragma unroll
  for (int o = 32; o; o >>= 1) v += __shfl_xor(v, o, 64);
  return v;
}

#define MFMA16(a,b,c) __builtin_amdgcn_mfma_f32_16x16x32_bf16((a),(b),(c),0,0,0)

// ---------------- prep: weight transposes (4-tile pipelined) + enc + qsbias --
// Each transpose block handles FOUR vertically-adjacent 64x64 tiles at one c0:
// load(t+1)->regs issued BEFORE write-out of tile t (T14), ds_write after.
// Output rows get 512B contiguous per block. Double-buffered LDS (33KB).
// flat grid regions:
//   [0,1024)      QKVO  (16 mats x 64 groups, R=C=1024)
//   [1024,2048)   Wf1   (4 mats x 256 groups, R=1024 C=4096)
//   [2048,3072)   Wf2   (4 mats x 256 groups, R=4096 C=1024)
//   [3072,4096)   enc f32->bf16
//   [4096,6144)   qsbias (4 layers x 512) -> bf16
__global__ __launch_bounds__(256) void prep_k(
    const float* __restrict__ Wq, const float* __restrict__ Wk,
    const float* __restrict__ Wv, const float* __restrict__ Wo,
    const float* __restrict__ Wf1, const float* __restrict__ Wf2,
    const float* __restrict__ enc, const float* __restrict__ dist,
    const float* __restrict__ Wth0, const float* __restrict__ bth0,
    const float* __restrict__ Wto0, const float* __restrict__ bto0,
    u16* __restrict__ Wqt, u16* __restrict__ Wkt,
    u16* __restrict__ Wvt, u16* __restrict__ Wot,
    u16* __restrict__ Wf1t, u16* __restrict__ Wf2t,
    u16* __restrict__ encb, u16* __restrict__ qs0){
  __shared__ float tile[2][64][65];
  const int t = blockIdx.x;
  if (t < 3072){
    const float* in; u16* out; int R, C, r0b, c0;
    if (t < 1024){
      const int mat = t >> 6, gi = t & 63, sel = mat >> 2, l = mat & 3;
      in  = (sel == 0 ? Wq : sel == 1 ? Wk : sel == 2 ? Wv : Wo) + (size_t)l * 1048576;
      out = (sel == 0 ? Wqt : sel == 1 ? Wkt : sel == 2 ? Wvt : Wot) + (size_t)l * 1048576;
      R = 1024; C = 1024; c0 = (gi >> 2) << 6; r0b = (gi & 3) << 8;
    } else if (t < 2048){
      const int t2 = t - 1024, mat = t2 >> 8, gi = t2 & 255;
      in = Wf1 + (size_t)mat * 4194304; out = Wf1t + (size_t)mat * 4194304;
      R = 1024; C = 4096; c0 = (gi >> 2) << 6; r0b = (gi & 3) << 8;
    } else {
      const int t2 = t - 2048, mat = t2 >> 8, gi = t2 & 255;
      in = Wf2 + (size_t)mat * 4194304; out = Wf2t + (size_t)mat * 4194304;
      R = 4096; C = 1024; c0 = (gi & 15) << 6; r0b = (gi >> 4) << 8;
    }
    const int rr0 = threadIdx.x >> 4, cc = (threadIdx.x & 15) * 4;
    float4 rv[4];

    auto LOADT = [&](int tt){
#pragma unroll
      for (int it = 0; it < 4; it++)
        rv[it] = *(const float4*)(in + (size_t)(r0b + tt*64 + rr0 + it*16) * C + c0 + cc);
    };
    auto DSW = [&](int buf){
#pragma unroll
      for (int it = 0; it < 4; it++){
        const int rr = rr0 + it*16;
        tile[buf][rr][cc]   = rv[it].x;
        tile[buf][rr][cc+1] = rv[it].y;
        tile[buf][rr][cc+2] = rv[it].z;
        tile[buf][rr][cc+3] = rv[it].w;
      }
    };
    auto WOUT = [&](int buf, int tt){
#pragma unroll
      for (int it2 = 0; it2 < 2; it2++){
        const int chunk = threadIdx.x + it2 * 256;
        const int c = chunk >> 3, q = (chunk & 7) * 8;
        union { u16x8 v8; u16 e[8]; } ob;
#pragma unroll
        for (int i = 0; i < 8; i++) ob.e[i] = f2bf(tile[buf][q + i][c]);
        *(u16x8*)(out + (size_t)(c0 + c) * R + r0b + tt*64 + q) = ob.v8;
      }
    };

    LOADT(0); DSW(0);
    __syncthreads();
#pragma unroll
    for (int tt = 0; tt < 4; tt++){
      const int buf = tt & 1;
      if (tt < 3) LOADT(tt + 1);          // loads in flight over write-out
      WOUT(buf, tt);
      if (tt < 3) DSW(buf ^ 1);
      __syncthreads();
    }
  } else if (t < 4096){                   // enc f32 -> bf16
    const int i = (t - 3072) * 256 + threadIdx.x;
    float4 v = ((const float4*)enc)[i];
    u16x4 o = { f2bf(v.x), f2bf(v.y), f2bf(v.z), f2bf(v.w) };
    ((u16x4*)encb)[i] = o;
  } else {                                // qsbias -> bf16
    const int bi = t - 4096, ly = bi >> 9, xi = bi & 511;
    const float* Wth = Wth0 + ly*32;
    const float* bth = bth0 + ly*32;
    const float* Wto = Wto0 + ly*32;
    u16* qs = qs0 + (size_t)ly * 524288;
    const int idx = xi * 256 + threadIdx.x;
    float4 s4 = ((const float4*)dist)[idx];
    float sv[4] = { s4.x, s4.y, s4.z, s4.w };
    float r[4];
    const float b0 = bto0[ly];
#pragma unroll
    for (int c = 0; c < 4; c++) r[c] = b0;
#pragma unroll
    for (int k = 0; k < 32; k++){
      const float wk = Wth[k], bk = bth[k], ok = Wto[k];
#pragma unroll
      for (int c = 0; c < 4; c++){
        float h = fmaxf(sv[c] * wk + bk, 0.0f);
        r[c] += h * ok;
      }
    }
    u16x4 o = { f2bf(r[0]), f2bf(r[1]), f2bf(r[2]), f2bf(r[3]) };
    ((u16x4*)qs)[idx] = o;
  }
}

// ---------------- layernorm: rows of 1024, (x-m)/(std+eps), bf16 out ----------
template<int COPY>
__global__ __launch_bounds__(256) void layernorm_k(const float* __restrict__ in,
                                                   float* __restrict__ x,
                                                   u16* __restrict__ outp){
  const int row = blockIdx.x;
  const int tid = threadIdx.x;
  const float4 v = ((const float4*)(in + (size_t)row * 1024))[tid];
  if (COPY) ((float4*)x)[(size_t)row * 256 + tid] = v;
  __shared__ float sb[8];
  const int wid = tid >> 6, lane = tid & 63;
  float s = wave_sum(v.x + v.y + v.z + v.w);
  if (lane == 0) sb[wid] = s;
  __syncthreads();
  const float mean = (sb[0] + sb[1] + sb[2] + sb[3]) * (1.0f / 1024.0f);
  const float dx = v.x - mean, dy = v.y - mean, dz = v.z - mean, dw = v.w - mean;
  float q = wave_sum(dx*dx + dy*dy + dz*dz + dw*dw);
  if (lane == 0) sb[4 + wid] = q;
  __syncthreads();
  const float sd = sqrtf((sb[4] + sb[5] + sb[6] + sb[7]) * (1.0f / 1024.0f));
  const float inv = 1.0f / (sd + 1e-6f);
  u16x4 o = { f2bf(dx*inv), f2bf(dy*inv), f2bf(dz*inv), f2bf(dw*inv) };
  ((u16x4*)outp)[(size_t)row * 256 + tid] = o;
}

// ---------------- 128xBN GEMM core, BK=64, 2-phase LDS double-buffer ---------
// C[M][Nd] = A[M][Krange] @ Bt[Nd][Krange]^T. 4 waves (2x2), each 64x(BN/2).
// T2 swizzle: linear gload_lds dest + inverse-swizzled global source chunk,
// reads XOR back (rule 21). MODE 0: bf16  3: bf16 relu(+bias)  5: f32 partial
// MODE 6: V^T scatter (row = n*64+h, col = b*512+t -> Vt[(b*16+n)*64+h][t])
template<int MODE, int BN>
DEVI void gemm128_core(const u16* A, int lda, const u16* Bt, int ldb,
                       int Klen, int Nd, void* Cout,
                       const float* bias, u16* Als, u16* Bls, int row0, int col0){
  constexpr int WN = BN / 2, FN = BN / 32;
  constexpr int BSZ = BN * 64;           // B-buffer elements per phase
  const int tid = threadIdx.x;
  const int wid = tid >> 6, lane = tid & 63;
  const int wm = wid >> 1, wn = wid & 1;
  const int lrow = lane & 15, g = lane >> 4, e7 = lane & 7;
  f32x4 acc[4][FN] = {};

  const int scol = ((lane & 7) ^ ((lane >> 3) & 7)) * 8;   // inverse-swizzled src chunk
  const u16* Ag = A + (size_t)(row0 + wid*8 + (lane >> 3)) * lda + scol;
  const u16* Bg = Bt + (size_t)(col0 + wid*8 + (lane >> 3)) * ldb + scol;
  const int dst0 = wid * 512;

  const int nt = Klen >> 6;

#define STAGE128(buf, k0)                                                     \
  {                                                                           \
    _Pragma("unroll")                                                         \
    for (int q = 0; q < 4; q++)                                               \
      gload16(Ag + (size_t)q*32*lda + (k0), Als + (buf)*8192 + dst0 + q*2048);\
    _Pragma("unroll")                                                         \
    for (int q = 0; q < BN/32; q++)                                           \
      gload16(Bg + (size_t)q*32*ldb + (k0), Bls + (buf)*BSZ + dst0 + q*2048); \
  }

  STAGE128(0, 0);
  __syncthreads();                       // compiler drains vmcnt before barrier

  for (int t = 0; t < nt; t++){
    const int cur = t & 1;
    if (t + 1 < nt) STAGE128(cur ^ 1, (t + 1) << 6);   // prefetch overlaps MFMA
    const u16* Ab = Als + cur * 8192;
    const u16* Bb = Bls + cur * BSZ;
#pragma unroll
    for (int ks = 0; ks < 2; ks++){
      const int sl = (((ks << 2) + g) ^ e7) << 3;
      u16x8 av[4], bv[FN];
#pragma unroll
      for (int mi = 0; mi < 4; mi++)
        av[mi] = *(const u16x8*)(Ab + (wm*64 + mi*16 + lrow) * 64 + sl);
#pragma unroll
      for (int ni = 0; ni < FN; ni++)
        bv[ni] = *(const u16x8*)(Bb + (wn*WN + ni*16 + lrow) * 64 + sl);
#pragma unroll
      for (int mi = 0; mi < 4; mi++)
#pragma unroll
        for (int ni = 0; ni < FN; ni++)
          acc[mi][ni] = MFMA16(av[mi], bv[ni], acc[mi][ni]);
    }
    __syncthreads();
  }
#undef STAGE128

#pragma unroll
  for (int mi = 0; mi < 4; mi++){
#pragma unroll
    for (int ni = 0; ni < FN; ni++){
      const int col = col0 + wn*WN + ni*16 + lrow;
#pragma unroll
      for (int j = 0; j < 4; j++){
        const int row = row0 + wm*64 + mi*16 + g*4 + j;
        float v = acc[mi][ni][j];
        if (MODE == 3) v = fmaxf(v + bias[col], 0.0f);
        if (MODE == 0 || MODE == 3)
          ((u16*)Cout)[(size_t)row * Nd + col] = f2bf(v);
        else if (MODE == 6)
          ((u16*)Cout)[(size_t)((col >> 9)*16 + (row >> 6)) * 32768
                       + (row & 63) * 512 + (col & 511)] = f2bf(v);
        else
          ((float*)Cout)[(size_t)row * Nd + col] = v;
      }
    }
  }
}

template<int MODE>
__global__ __launch_bounds__(256) void gemm128_k(const u16* __restrict__ A, int lda,
    const u16* __restrict__ Bt, int ldb, int Klen, int Nd, void* __restrict__ Cout,
    const float* __restrict__ bias){
  __shared__ __align__(16) u16 Als[2 * 8192];
  __shared__ __align__(16) u16 Bls[2 * 4096];
  gemm128_core<MODE, 64>(A, lda, Bt, ldb, Klen, Nd, Cout, bias,
                         Als, Bls, blockIdx.y * 128, blockIdx.x * 64);
}

// K-proj (normal) + V-proj (transposed output) for ALL layers: z in [0,8)
__global__ __launch_bounds__(256) void gemmKV_k(const u16* __restrict__ encb,
    const u16* __restrict__ Wkt, const u16* __restrict__ Wvt,
    u16* __restrict__ Kb, u16* __restrict__ Vt){
  __shared__ __align__(16) u16 Als[2 * 8192];
  __shared__ __align__(16) u16 Bls[2 * 4096];
  const int z = blockIdx.z, l = z >> 1;
  if ((z & 1) == 0)
    gemm128_core<0, 64>(encb, 1024, Wkt + (size_t)l*1048576, 1024, 1024, 1024,
                        Kb + (size_t)l*1048576, nullptr,
                        Als, Bls, blockIdx.y * 128, blockIdx.x * 64);
  else   // C[h'][b*512+t] = Wvt @ encb^T, scattered into Vt[(b,n,h),t]
    gemm128_core<6, 64>(Wvt + (size_t)l*1048576, 1024, encb, 1024, 1024, 1024,
                        Vt + (size_t)l*1048576, nullptr,
                        Als, Bls, blockIdx.y * 128, blockIdx.x * 64);
}

// split-K=4 GEMM into f32 partials (Nd=1024 always)
__global__ __launch_bounds__(256) void gemm_splitk_k(const u16* __restrict__ A, int lda,
    const u16* __restrict__ Bt, int ldb, int Klen, float* __restrict__ part){
  __shared__ __align__(16) u16 Als[2 * 8192];
  __shared__ __align__(16) u16 Bls[2 * 4096];
  const int z = blockIdx.z;
  gemm128_core<5, 64>(A + (size_t)z * Klen, lda, Bt + (size_t)z * Klen, ldb, Klen, 1024,
                      part + (size_t)z * 1048576, nullptr,
                      Als, Bls, blockIdx.y * 128, blockIdx.x * 64);
}

// ---------------- reduce + layernorm ----------------
// x += sum(part) [+ bias]; then LN(x) -> xn (bf16) or dout (f32, LAST)
template<int BIAS, int LAST>
__global__ __launch_bounds__(256) void reduce_ln_k(const float* __restrict__ part,
    const float* __restrict__ bias, float* __restrict__ x, u16* __restrict__ xn,
    float* __restrict__ dout){
  const int row = blockIdx.x, tid = threadIdx.x;
  const size_t idx = (size_t)row * 256 + tid;
  float4 v = ((const float4*)x)[idx];
  float4 p0 = ((const float4*)part)[idx];
  float4 p1 = ((const float4*)(part + 1048576))[idx];
  float4 p2 = ((const float4*)(part + 2097152))[idx];
  float4 p3 = ((const float4*)(part + 3145728))[idx];
  v.x += p0.x + p1.x + p2.x + p3.x;
  v.y += p0.y + p1.y + p2.y + p3.y;
  v.z += p0.z + p1.z + p2.z + p3.z;
  v.w += p0.w + p1.w + p2.w + p3.w;
  if (BIAS){
    const float4 b = *(const float4*)(bias + tid * 4);
    v.x += b.x; v.y += b.y; v.z += b.z; v.w += b.w;
  }
  if (!LAST) ((float4*)x)[idx] = v;        // residual carried forward

  __shared__ float sb[8];
  const int wid = tid >> 6, lane = tid & 63;
  float s = wave_sum(v.x + v.y + v.z + v.w);
  if (lane == 0) sb[wid] = s;
  __syncthreads();
  const float mean = (sb[0] + sb[1] + sb[2] + sb[3]) * (1.0f / 1024.0f);
  const float dx = v.x - mean, dy = v.y - mean, dz = v.z - mean, dw = v.w - mean;
  float q = wave_sum(dx*dx + dy*dy + dz*dz + dw*dw);
  if (lane == 0) sb[4 + wid] = q;
  __syncthreads();
  const float sd = sqrtf((sb[4] + sb[5] + sb[6] + sb[7]) * (1.0f / 1024.0f));
  const float inv = 1.0f / (sd + 1e-6f);
  if (LAST){
    ((float4*)dout)[idx] = make_float4(dx*inv, dy*inv, dz*inv, dw*inv);
  } else {
    u16x4 o = { f2bf(dx*inv), f2bf(dy*inv), f2bf(dz*inv), f2bf(dw*inv) };
    ((u16x4*)xn)[idx] = o;
  }
}

// ---------------- fused flash attention (Q-projection fused in) -------------
// grid (n=16, ftile=8, b=2); 4 waves, wave w owns 16 q-rows. 2 blocks/CU.
// Phase A: 64x64x1024 mini-GEMM Q = xn_tile @ Wqt_slice (2-phase staged),
//          Q*H^-0.5 -> swizzled LDS tile -> per-wave B-frags.
// Phase B: S^T = mfma(K, Q^T): lane holds S[fw+l15][t]; row softmax lane-local.
// Phase C: P -> per-wave LDS (swizzled), PV = mfma(P, V^T) from L2.
__global__ __launch_bounds__(256, 2) void attn_k(const u16* __restrict__ xn,
    const u16* __restrict__ Wqt,
    const u16* __restrict__ Kb, const u16* __restrict__ Vt,
    const u16* __restrict__ qs, const float* __restrict__ abias,
    u16* __restrict__ aout){
  const int n = blockIdx.x, f0 = blockIdx.y * 64, b = blockIdx.z;
  const int w = threadIdx.x >> 6, lane = threadIdx.x & 63;
  const int l15 = lane & 15, g = lane >> 4, e7 = lane & 7;
  const int fw = f0 + w * 16;
  __shared__ __align__(16) u16 Pl[4][16 * 512];   // 64 KB
  u16* pw = &Pl[w][0];

  u16x8 qf0, qf1;
  {
    // ---- Q mini-GEMM: A = xn rows [b*512+f0, +64), Bt = Wqt rows [n*64, +64)
    u16* Als = &Pl[0][0];          // 2 bufs x 4096 elems = 16 KB
    u16* Bls = &Pl[1][0];
    const int wm = w >> 1, wn = w & 1;
    f32x4 qac[2][2] = {};
    const int scol = ((lane & 7) ^ ((lane >> 3) & 7)) * 8;
    const u16* Ag = xn + (size_t)(b*512 + f0 + w*8 + (lane >> 3)) * 1024 + scol;
    const u16* Bg = Wqt + (size_t)(n*64 + w*8 + (lane >> 3)) * 1024 + scol;
    const int dq = w * 512;

#define STAGEQ(buf, k0)                                         \
    gload16(Ag + (k0),            Als + (buf)*4096 + dq);       \
    gload16(Ag + 32*1024 + (k0),  Als + (buf)*4096 + dq + 2048);\
    gload16(Bg + (k0),            Bls + (buf)*4096 + dq);       \
    gload16(Bg + 32*1024 + (k0),  Bls + (buf)*4096 + dq + 2048);

    STAGEQ(0, 0);
    __syncthreads();
    for (int t = 0; t < 16; t++){
      const int cur = t & 1;
      if (t < 15){ STAGEQ(cur ^ 1, (t + 1) << 6); }
      const u16* Ab = Als + cur * 4096;
      const u16* Bb = Bls + cur * 4096;
#pragma unroll
      for (int ks = 0; ks < 2; ks++){
        const int sl = (((ks << 2) + g) ^ e7) << 3;
        u16x8 av[2], bv[2];
#pragma unroll
        for (int mi = 0; mi < 2; mi++)
          av[mi] = *(const u16x8*)(Ab + (wm*32 + mi*16 + l15) * 64 + sl);
#pragma unroll
        for (int ni = 0; ni < 2; ni++)
          bv[ni] = *(const u16x8*)(Bb + (wn*32 + ni*16 + l15) * 64 + sl);
#pragma unroll
        for (int mi = 0; mi < 2; mi++)
#pragma unroll
          for (int ni = 0; ni < 2; ni++)
            qac[mi][ni] = MFMA16(av[mi], bv[ni], qac[mi][ni]);
      }
      __syncthreads();
    }
#undef STAGEQ

    // write Q*0.125 to swizzled 64x64 tile in Pl[2] (untouched by staging)
    u16* Qt = &Pl[2][0];
#pragma unroll
    for (int mi = 0; mi < 2; mi++)
#pragma unroll
      for (int ni = 0; ni < 2; ni++)
#pragma unroll
        for (int j = 0; j < 4; j++){
          const int r = wm*32 + mi*16 + g*4 + j;
          const int c = wn*32 + ni*16 + l15;
          const int byte = r*128 + (((c >> 3) ^ (r & 7)) << 4) + (c & 7)*2;
          *(u16*)((char*)Qt + byte) = f2bf(qac[mi][ni][j] * 0.125f);
        }
    __syncthreads();
    // read this wave's B-frags: row = w*16+l15, k-chunks g and 4+g
    const int r = w*16 + l15;
    const char* qrow = (char*)Qt + r*128;
    qf0 = *(const u16x8*)(qrow + ((g ^ (r & 7)) << 4));
    qf1 = *(const u16x8*)(qrow + (((4 + g) ^ (r & 7)) << 4));
    __syncthreads();   // all frag reads done before P-phase overwrites LDS
  }

  // QK^T: acc[tf] holds S[fw+l15][tf*16 + g*4 + j]
  f32x4 acc[32];
  const u16* kp = Kb + ((size_t)b*512 + l15) * 1024 + n*64 + g*8;
#pragma unroll
  for (int tf = 0; tf < 32; tf++){
    u16x8 k0 = *(const u16x8*)(kp + (size_t)tf*16*1024);
    u16x8 k1 = *(const u16x8*)(kp + (size_t)tf*16*1024 + 32);
    f32x4 z = {0.f, 0.f, 0.f, 0.f};
    z = MFMA16(k0, qf0, z);
    acc[tf] = MFMA16(k1, qf1, z);
  }

  // + qs bias (bf16) + attn bias, row max
  const u16* qsp = qs + ((size_t)b*512 + fw + l15) * 512 + g*4;
  const float* abp = abias + (size_t)b*512 + g*4;
  float m = -3.0e38f;
#pragma unroll
  for (int tf = 0; tf < 32; tf++){
    u16x4 qv = *(const u16x4*)(qsp + tf*16);
    float4 av = *(const float4*)(abp + tf*16);
    acc[tf][0] += bf2f(qv[0]) + av.x;
    acc[tf][1] += bf2f(qv[1]) + av.y;
    acc[tf][2] += bf2f(qv[2]) + av.z;
    acc[tf][3] += bf2f(qv[3]) + av.w;
    m = fmaxf(m, fmaxf(fmaxf(acc[tf][0], acc[tf][1]), fmaxf(acc[tf][2], acc[tf][3])));
  }
  m = fmaxf(m, __shfl_xor(m, 16, 64));
  m = fmaxf(m, __shfl_xor(m, 32, 64));

  float s = 0.f;
#pragma unroll
  for (int tf = 0; tf < 32; tf++){
#pragma unroll
    for (int j = 0; j < 4; j++){
      float e = __expf(acc[tf][j] - m);
      acc[tf][j] = e; s += e;
    }
  }
  s += __shfl_xor(s, 16, 64);
  s += __shfl_xor(s, 32, 64);
  const float inv = 1.0f / s;
  float invj[4];
#pragma unroll
  for (int j = 0; j < 4; j++) invj[j] = __shfl(inv, g*4 + j, 64);  // inv for row g*4+j

  // store unnormalized P (<=1) row-major [16][512] bf16, chunk-swizzled
#pragma unroll
  for (int tf = 0; tf < 32; tf++){
    const int chunk = tf*2 + (g >> 1);
    const int boff = (l15 << 10) + ((chunk ^ e7) << 4) + ((g & 1) << 3);
    u16x4 pk = { f2bf(acc[tf][0]), f2bf(acc[tf][1]), f2bf(acc[tf][2]), f2bf(acc[tf][3]) };
    *(u16x4*)((char*)pw + boff) = pk;
  }

  // PV: O[f][h] = P[f][:] @ V[:][h];  V^T frags direct from global (L2-resident)
  f32x4 oacc[4] = {};
  const u16* vp = Vt + ((size_t)(b*16 + n)*64 + l15) * 512 + g*8;
  for (int kk = 0; kk < 16; kk++){
    u16x8 pa = *(const u16x8*)((char*)pw + (l15 << 10) + ((((kk << 2) + g) ^ e7) << 4));
#pragma unroll
    for (int nf = 0; nf < 4; nf++){
      u16x8 vb = *(const u16x8*)(vp + (size_t)nf*16*512 + kk*32);
      oacc[nf] = MFMA16(pa, vb, oacc[nf]);
    }
  }

  u16* op = aout + ((size_t)b*512 + fw + g*4) * 1024 + n*64 + l15;
#pragma unroll
  for (int nf = 0; nf < 4; nf++)
#pragma unroll
    for (int j = 0; j < 4; j++)
      op[(size_t)j*1024 + nf*16] = f2bf(oacc[nf][j] * invj[j]);
}

// ---------------- host ----------------
extern "C" void kernel_launch(void* const* d_in, const int* in_sizes, int n_in,
                              void* d_out, int out_size, void* d_ws, size_t ws_size,
                              hipStream_t stream){
  const float* dec_in   = (const float*)d_in[0];
  const float* enc      = (const float*)d_in[1];
  const float* dist     = (const float*)d_in[3];
  const float* abias    = (const float*)d_in[5];
  const float* Wq  = (const float*)d_in[6];
  const float* Wk  = (const float*)d_in[7];
  const float* Wv  = (const float*)d_in[8];
  const float* Wo  = (const float*)d_in[9];
  const float* Wth = (const float*)d_in[10];
  const float* bth = (const float*)d_in[11];
  const float* Wto = (const float*)d_in[12];
  const float* bto = (const float*)d_in[13];
  const float* Wf1 = (const float*)d_in[14];
  const float* bf1 = (const float*)d_in[15];
  const float* Wf2 = (const float*)d_in[16];
  const float* bf2 = (const float*)d_in[17];
  float* dout = (float*)d_out;

  char* wp = (char*)d_ws;
  auto alloc = [&](size_t n) -> char* {
    char* p = wp; wp += (n + 255) & ~(size_t)255; return p;
  };
  float* x     = (float*)alloc((size_t)1048576 * 4);
  u16*  xn     = (u16*)alloc((size_t)1048576 * 2);
  u16*  encb   = (u16*)alloc((size_t)1048576 * 2);
  u16*  Wqt    = (u16*)alloc((size_t)4194304 * 2);    // 4 layers
  u16*  Wkt    = (u16*)alloc((size_t)4194304 * 2);
  u16*  Wvt    = (u16*)alloc((size_t)4194304 * 2);
  u16*  Wot    = (u16*)alloc((size_t)4194304 * 2);
  u16*  Wf1t   = (u16*)alloc((size_t)16777216 * 2);   // 4 layers
  u16*  Wf2t   = (u16*)alloc((size_t)16777216 * 2);
  u16*  Kb     = (u16*)alloc((size_t)4194304 * 2);    // 4 layers
  u16*  Vt     = (u16*)alloc((size_t)4194304 * 2);
  u16*  qs     = (u16*)alloc((size_t)2097152 * 2);    // 4 layers, bf16
  u16*  aout   = (u16*)alloc((size_t)1048576 * 2);
  u16*  ffh    = (u16*)alloc((size_t)4194304 * 2);
  float* part  = (float*)alloc((size_t)4194304 * 4);  // 4x 1024x1024 f32

  // ---- upfront (3 dispatches) ----
  prep_k<<<6144, 256, 0, stream>>>(Wq, Wk, Wv, Wo, Wf1, Wf2, enc, dist,
                                   Wth, bth, Wto, bto,
                                   Wqt, Wkt, Wvt, Wot, Wf1t, Wf2t, encb, qs);
  gemmKV_k<<<dim3(16, 8, 8), 256, 0, stream>>>(encb, Wkt, Wvt, Kb, Vt);
  layernorm_k<1><<<1024, 256, 0, stream>>>(dec_in, x, xn);

  // ---- per-layer serial chain: 6 dispatches ----
  for (int i = 0; i < 4; i++){
    const size_t wo = (size_t)i * 1048576;

    // fused attention (Q-proj + logits + biases + softmax + PV)
    attn_k<<<dim3(16, 8, 2), 256, 0, stream>>>(xn, Wqt + wo, Kb + wo, Vt + wo,
                                               qs + (size_t)i * 524288, abias, aout);

    // O projection (split-K=4) + fused residual+LN
    gemm_splitk_k<<<dim3(16, 8, 4), 256, 0, stream>>>(aout, 1024, Wot + wo, 1024, 256, part);
    reduce_ln_k<0, 0><<<1024, 256, 0, stream>>>(part, nullptr, x, xn, nullptr);

    // FFN
    gemm128_k<3><<<dim3(64, 8), 256, 0, stream>>>(xn, 1024, Wf1t + (size_t)i*4194304, 1024,
                                                  1024, 4096, ffh, bf1 + (size_t)i*4096);
    gemm_splitk_k<<<dim3(16, 8, 4), 256, 0, stream>>>(ffh, 4096, Wf2t + (size_t)i*4194304, 4096,
                                                      1024, part);
    if (i < 3)
      reduce_ln_k<1, 0><<<1024, 256, 0, stream>>>(part, bf2 + (size_t)i*1024, x, xn, nullptr);
    else
      reduce_ln_k<1, 1><<<1024, 256, 0, stream>>>(part, bf2 + (size_t)i*1024, x, nullptr, dout);
  }
}

// Round 13
// 431.423 us; speedup vs baseline: 1.0859x; 1.0324x over previous
//
#include <hip/hip_runtime.h>

typedef unsigned short u16;
typedef __attribute__((ext_vector_type(8))) unsigned short u16x8;
typedef __attribute__((ext_vector_type(4))) unsigned short u16x4;
typedef __attribute__((ext_vector_type(4))) float f32x4;

#define DEVI __device__ __forceinline__

// ---------------- helpers ----------------
DEVI u16 f2bf(float f){
  unsigned u = __float_as_uint(f);
  u += 0x7FFFu + ((u >> 16) & 1u);      // round-to-nearest-even
  return (u16)(u >> 16);
}

DEVI float bf2f(u16 b){
  return __uint_as_float((unsigned)b << 16);
}

DEVI void gload16(const void* g, void* l){
  __builtin_amdgcn_global_load_lds((const __attribute__((address_space(1))) void*)g,
                                   (__attribute__((address_space(3))) void*)l, 16, 0, 0);
}

DEVI float wave_sum(float v){
#pragma unroll
  for (int o = 32; o; o >>= 1) v += __shfl_xor(v, o, 64);
  return v;
}

#define MFMA16(a,b,c) __builtin_amdgcn_mfma_f32_16x16x32_bf16((a),(b),(c),0,0,0)

// ---------------- 4-tile pipelined 64x64 transpose group (256x64 region) ----
// tb points to float[2][64][65] in LDS.
DEVI void trans4(const float* __restrict__ in, u16* __restrict__ out,
                 int R, int C, int r0b, int c0, float* tb){
  const int rr0 = threadIdx.x >> 4, cc = (threadIdx.x & 15) * 4;
  float4 rv[4];
#define TLOAD(tt)                                                             \
  { _Pragma("unroll")                                                         \
    for (int it = 0; it < 4; it++)                                            \
      rv[it] = *(const float4*)(in + (size_t)(r0b + (tt)*64 + rr0 + it*16) * C + c0 + cc); }
#define TDSW(buf)                                                             \
  { _Pragma("unroll")                                                         \
    for (int it = 0; it < 4; it++){                                           \
      const int rr = rr0 + it*16;                                             \
      float* tr = tb + ((buf)*64 + rr) * 65 + cc;                             \
      tr[0] = rv[it].x; tr[1] = rv[it].y; tr[2] = rv[it].z; tr[3] = rv[it].w; } }
#define TWOUT(buf, tt)                                                        \
  { _Pragma("unroll")                                                         \
    for (int it2 = 0; it2 < 2; it2++){                                        \
      const int chunk = threadIdx.x + it2 * 256;                              \
      const int c = chunk >> 3, q = (chunk & 7) * 8;                          \
      union { u16x8 v8; u16 e[8]; } ob;                                       \
      _Pragma("unroll")                                                       \
      for (int i = 0; i < 8; i++) ob.e[i] = f2bf(tb[((buf)*64 + q + i) * 65 + c]); \
      *(u16x8*)(out + (size_t)(c0 + c) * R + r0b + (tt)*64 + q) = ob.v8; } }

  TLOAD(0); TDSW(0);
  __syncthreads();
#pragma unroll
  for (int tt = 0; tt < 4; tt++){
    const int buf = tt & 1;
    if (tt < 3) TLOAD(tt + 1);           // loads in flight over write-out
    TWOUT(buf, tt);
    if (tt < 3) TDSW(buf ^ 1);
    __syncthreads();
  }
#undef TLOAD
#undef TDSW
#undef TWOUT
}

// ---------------- prep_A: Wk/Wv transposes + enc convert + LN(dec_in) -------
// flat: [0,512) Wk/Wv  [512,1536) enc  [1536,2560) LN+copy
__global__ __launch_bounds__(256) void prepA_k(
    const float* __restrict__ Wk, const float* __restrict__ Wv,
    const float* __restrict__ enc, const float* __restrict__ dec_in,
    float* __restrict__ x, u16* __restrict__ xn,
    u16* __restrict__ Wkt, u16* __restrict__ Wvt, u16* __restrict__ encb){
  __shared__ __align__(16) float tb[2 * 64 * 65];
  const int t = blockIdx.x;
  if (t < 512){
    const int sel = t >> 8, t2 = t & 255, mat = t2 >> 6, gi = t2 & 63;
    const float* in = (sel ? Wv : Wk) + (size_t)mat * 1048576;
    u16* out = (sel ? Wvt : Wkt) + (size_t)mat * 1048576;
    trans4(in, out, 1024, 1024, (gi & 3) << 8, (gi >> 2) << 6, tb);
  } else if (t < 1536){                   // enc f32 -> bf16
    const int i = (t - 512) * 256 + threadIdx.x;
    float4 v = ((const float4*)enc)[i];
    u16x4 o = { f2bf(v.x), f2bf(v.y), f2bf(v.z), f2bf(v.w) };
    ((u16x4*)encb)[i] = o;
  } else {                                // LN + residual copy
    const int row = t - 1536, tid = threadIdx.x;
    const float4 v = ((const float4*)(dec_in + (size_t)row * 1024))[tid];
    ((float4*)x)[(size_t)row * 256 + tid] = v;
    __shared__ float sb[8];
    const int wid = tid >> 6, lane = tid & 63;
    float s = wave_sum(v.x + v.y + v.z + v.w);
    if (lane == 0) sb[wid] = s;
    __syncthreads();
    const float mean = (sb[0] + sb[1] + sb[2] + sb[3]) * (1.0f / 1024.0f);
    const float dx = v.x - mean, dy = v.y - mean, dz = v.z - mean, dw = v.w - mean;
    float q = wave_sum(dx*dx + dy*dy + dz*dz + dw*dw);
    if (lane == 0) sb[4 + wid] = q;
    __syncthreads();
    const float sd = sqrtf((sb[4] + sb[5] + sb[6] + sb[7]) * (1.0f / 1024.0f));
    const float inv = 1.0f / (sd + 1e-6f);
    u16x4 o = { f2bf(dx*inv), f2bf(dy*inv), f2bf(dz*inv), f2bf(dw*inv) };
    ((u16x4*)xn)[(size_t)row * 256 + tid] = o;
  }
}

// ---------------- 128xBN GEMM core (unchanged, proven) -----------------------
// MODE 0: bf16  3: bf16 relu(+bias)  5: f32 partial  6: V^T scatter
template<int MODE, int BN>
DEVI void gemm128_core(const u16* A, int lda, const u16* Bt, int ldb,
                       int Klen, int Nd, void* Cout,
                       const float* bias, u16* Als, u16* Bls, int row0, int col0){
  constexpr int WN = BN / 2, FN = BN / 32;
  constexpr int BSZ = BN * 64;
  const int tid = threadIdx.x;
  const int wid = tid >> 6, lane = tid & 63;
  const int wm = wid >> 1, wn = wid & 1;
  const int lrow = lane & 15, g = lane >> 4, e7 = lane & 7;
  f32x4 acc[4][FN] = {};

  const int scol = ((lane & 7) ^ ((lane >> 3) & 7)) * 8;
  const u16* Ag = A + (size_t)(row0 + wid*8 + (lane >> 3)) * lda + scol;
  const u16* Bg = Bt + (size_t)(col0 + wid*8 + (lane >> 3)) * ldb + scol;
  const int dst0 = wid * 512;
  const int nt = Klen >> 6;

#define STAGE128(buf, k0)                                                     \
  {                                                                           \
    _Pragma("unroll")                                                         \
    for (int q = 0; q < 4; q++)                                               \
      gload16(Ag + (size_t)q*32*lda + (k0), Als + (buf)*8192 + dst0 + q*2048);\
    _Pragma("unroll")                                                         \
    for (int q = 0; q < BN/32; q++)                                           \
      gload16(Bg + (size_t)q*32*ldb + (k0), Bls + (buf)*BSZ + dst0 + q*2048); \
  }

  STAGE128(0, 0);
  __syncthreads();

  for (int t = 0; t < nt; t++){
    const int cur = t & 1;
    if (t + 1 < nt) STAGE128(cur ^ 1, (t + 1) << 6);
    const u16* Ab = Als + cur * 8192;
    const u16* Bb = Bls + cur * BSZ;
#pragma unroll
    for (int ks = 0; ks < 2; ks++){
      const int sl = (((ks << 2) + g) ^ e7) << 3;
      u16x8 av[4], bv[FN];
#pragma unroll
      for (int mi = 0; mi < 4; mi++)
        av[mi] = *(const u16x8*)(Ab + (wm*64 + mi*16 + lrow) * 64 + sl);
#pragma unroll
      for (int ni = 0; ni < FN; ni++)
        bv[ni] = *(const u16x8*)(Bb + (wn*WN + ni*16 + lrow) * 64 + sl);
#pragma unroll
      for (int mi = 0; mi < 4; mi++)
#pragma unroll
        for (int ni = 0; ni < FN; ni++)
          acc[mi][ni] = MFMA16(av[mi], bv[ni], acc[mi][ni]);
    }
    __syncthreads();
  }
#undef STAGE128

#pragma unroll
  for (int mi = 0; mi < 4; mi++){
#pragma unroll
    for (int ni = 0; ni < FN; ni++){
      const int col = col0 + wn*WN + ni*16 + lrow;
#pragma unroll
      for (int j = 0; j < 4; j++){
        const int row = row0 + wm*64 + mi*16 + g*4 + j;
        float v = acc[mi][ni][j];
        if (MODE == 3) v = fmaxf(v + bias[col], 0.0f);
        if (MODE == 0 || MODE == 3)
          ((u16*)Cout)[(size_t)row * Nd + col] = f2bf(v);
        else if (MODE == 6)
          ((u16*)Cout)[(size_t)((col >> 9)*16 + (row >> 6)) * 32768
                       + (row & 63) * 512 + (col & 511)] = f2bf(v);
        else
          ((float*)Cout)[(size_t)row * Nd + col] = v;
      }
    }
  }
}

// ---------------- prep_B + gemmKV merged: one flat dispatch ------------------
// Transpose/qs blocks (HBM-heavy) co-run with gemmKV blocks (MFMA-heavy).
// flat regions:
//   [0,256)       Wq transpose (4 mats x 64 groups)
//   [256,1280)    Wf1 (4 mats x 256 groups, R=1024 C=4096)
//   [1280,2304)   Wf2 (4 mats x 256 groups, R=4096 C=1024)
//   [2304,4352)   qsbias (4 layers x 512) -> bf16
//   [4352,5376)   gemmKV (1024 blocks: z=8, y=8, x=16)
__global__ __launch_bounds__(256) void prepB_gemmKV_k(
    const float* __restrict__ Wq, const float* __restrict__ Wf1,
    const float* __restrict__ Wf2, const float* __restrict__ dist,
    const float* __restrict__ Wth0, const float* __restrict__ bth0,
    const float* __restrict__ Wto0, const float* __restrict__ bto0,
    const u16* __restrict__ encb, const u16* __restrict__ Wkt,
    const u16* __restrict__ Wvt,
    u16* __restrict__ Wqt, u16* __restrict__ Wf1t, u16* __restrict__ Wf2t,
    u16* __restrict__ qs0, u16* __restrict__ Kb, u16* __restrict__ Vt){
  __shared__ __align__(16) char smem[49152];
  const int t = blockIdx.x;
  if (t < 2304){
    float* tb = (float*)smem;
    if (t < 256){
      const int mat = t >> 6, gi = t & 63;
      trans4(Wq + (size_t)mat * 1048576, Wqt + (size_t)mat * 1048576,
             1024, 1024, (gi & 3) << 8, (gi >> 2) << 6, tb);
    } else if (t < 1280){
      const int t2 = t - 256, mat = t2 >> 8, gi = t2 & 255;
      trans4(Wf1 + (size_t)mat * 4194304, Wf1t + (size_t)mat * 4194304,
             1024, 4096, (gi & 3) << 8, (gi >> 2) << 6, tb);
    } else {
      const int t2 = t - 1280, mat = t2 >> 8, gi = t2 & 255;
      trans4(Wf2 + (size_t)mat * 4194304, Wf2t + (size_t)mat * 4194304,
             4096, 1024, (gi >> 4) << 8, (gi & 15) << 6, tb);
    }
  } else if (t < 4352){                   // qsbias -> bf16
    const int bi = t - 2304, ly = bi >> 9, xi = bi & 511;
    const float* Wth = Wth0 + ly*32;
    const float* bth = bth0 + ly*32;
    const float* Wto = Wto0 + ly*32;
    u16* qs = qs0 + (size_t)ly * 524288;
    const int idx = xi * 256 + threadIdx.x;
    float4 s4 = ((const float4*)dist)[idx];
    float sv[4] = { s4.x, s4.y, s4.z, s4.w };
    float r[4];
    const float b0 = bto0[ly];
#pragma unroll
    for (int c = 0; c < 4; c++) r[c] = b0;
#pragma unroll
    for (int k = 0; k < 32; k++){
      const float wk = Wth[k], bk = bth[k], ok = Wto[k];
#pragma unroll
      for (int c = 0; c < 4; c++){
        float h = fmaxf(sv[c] * wk + bk, 0.0f);
        r[c] += h * ok;
      }
    }
    u16x4 o = { f2bf(r[0]), f2bf(r[1]), f2bf(r[2]), f2bf(r[3]) };
    ((u16x4*)qs)[idx] = o;
  } else {                                // gemmKV
    u16* Als = (u16*)smem;                // 2*8192 elems = 32 KB
    u16* Bls = (u16*)(smem + 32768);      // 2*4096 elems = 16 KB
    const int t2 = t - 4352;
    const int z = t2 >> 7, rem = t2 & 127;
    const int y = rem >> 4, xb = rem & 15;
    const int l = z >> 1;
    if ((z & 1) == 0)
      gemm128_core<0, 64>(encb, 1024, Wkt + (size_t)l*1048576, 1024, 1024, 1024,
                          Kb + (size_t)l*1048576, nullptr,
                          Als, Bls, y * 128, xb * 64);
    else   // C[h'][b*512+t] = Wvt @ encb^T, scattered into Vt[(b,n,h),t]
      gemm128_core<6, 64>(Wvt + (size_t)l*1048576, 1024, encb, 1024, 1024, 1024,
                          Vt + (size_t)l*1048576, nullptr,
                          Als, Bls, y * 128, xb * 64);
  }
}

template<int MODE>
__global__ __launch_bounds__(256) void gemm128_k(const u16* __restrict__ A, int lda,
    const u16* __restrict__ Bt, int ldb, int Klen, int Nd, void* __restrict__ Cout,
    const float* __restrict__ bias){
  __shared__ __align__(16) u16 Als[2 * 8192];
  __shared__ __align__(16) u16 Bls[2 * 4096];
  gemm128_core<MODE, 64>(A, lda, Bt, ldb, Klen, Nd, Cout, bias,
                         Als, Bls, blockIdx.y * 128, blockIdx.x * 64);
}

// split-K=4 GEMM into f32 partials (Nd=1024 always)
__global__ __launch_bounds__(256) void gemm_splitk_k(const u16* __restrict__ A, int lda,
    const u16* __restrict__ Bt, int ldb, int Klen, float* __restrict__ part){
  __shared__ __align__(16) u16 Als[2 * 8192];
  __shared__ __align__(16) u16 Bls[2 * 4096];
  const int z = blockIdx.z;
  gemm128_core<5, 64>(A + (size_t)z * Klen, lda, Bt + (size_t)z * Klen, ldb, Klen, 1024,
                      part + (size_t)z * 1048576, nullptr,
                      Als, Bls, blockIdx.y * 128, blockIdx.x * 64);
}

// ---------------- reduce + layernorm ----------------
template<int BIAS, int LAST>
__global__ __launch_bounds__(256) void reduce_ln_k(const float* __restrict__ part,
    const float* __restrict__ bias, float* __restrict__ x, u16* __restrict__ xn,
    float* __restrict__ dout){
  const int row = blockIdx.x, tid = threadIdx.x;
  const size_t idx = (size_t)row * 256 + tid;
  float4 v = ((const float4*)x)[idx];
  float4 p0 = ((const float4*)part)[idx];
  float4 p1 = ((const float4*)(part + 1048576))[idx];
  float4 p2 = ((const float4*)(part + 2097152))[idx];
  float4 p3 = ((const float4*)(part + 3145728))[idx];
  v.x += p0.x + p1.x + p2.x + p3.x;
  v.y += p0.y + p1.y + p2.y + p3.y;
  v.z += p0.z + p1.z + p2.z + p3.z;
  v.w += p0.w + p1.w + p2.w + p3.w;
  if (BIAS){
    const float4 b = *(const float4*)(bias + tid * 4);
    v.x += b.x; v.y += b.y; v.z += b.z; v.w += b.w;
  }
  if (!LAST) ((float4*)x)[idx] = v;

  __shared__ float sb[8];
  const int wid = tid >> 6, lane = tid & 63;
  float s = wave_sum(v.x + v.y + v.z + v.w);
  if (lane == 0) sb[wid] = s;
  __syncthreads();
  const float mean = (sb[0] + sb[1] + sb[2] + sb[3]) * (1.0f / 1024.0f);
  const float dx = v.x - mean, dy = v.y - mean, dz = v.z - mean, dw = v.w - mean;
  float q = wave_sum(dx*dx + dy*dy + dz*dz + dw*dw);
  if (lane == 0) sb[4 + wid] = q;
  __syncthreads();
  const float sd = sqrtf((sb[4] + sb[5] + sb[6] + sb[7]) * (1.0f / 1024.0f));
  const float inv = 1.0f / (sd + 1e-6f);
  if (LAST){
    ((float4*)dout)[idx] = make_float4(dx*inv, dy*inv, dz*inv, dw*inv);
  } else {
    u16x4 o = { f2bf(dx*inv), f2bf(dy*inv), f2bf(dz*inv), f2bf(dw*inv) };
    ((u16x4*)xn)[idx] = o;
  }
}

// ---------------- fused flash attention (Q-projection fused in) -------------
// grid (n=16, ftile=8, b=2); 4 waves, wave w owns 16 q-rows. 2 blocks/CU.
__global__ __launch_bounds__(256, 2) void attn_k(const u16* __restrict__ xn,
    const u16* __restrict__ Wqt,
    const u16* __restrict__ Kb, const u16* __restrict__ Vt,
    const u16* __restrict__ qs, const float* __restrict__ abias,
    u16* __restrict__ aout){
  const int n = blockIdx.x, f0 = blockIdx.y * 64, b = blockIdx.z;
  const int w = threadIdx.x >> 6, lane = threadIdx.x & 63;
  const int l15 = lane & 15, g = lane >> 4, e7 = lane & 7;
  const int fw = f0 + w * 16;
  __shared__ __align__(16) u16 Pl[4][16 * 512];   // 64 KB
  u16* pw = &Pl[w][0];

  u16x8 qf0, qf1;
  {
    u16* Als = &Pl[0][0];
    u16* Bls = &Pl[1][0];
    const int wm = w >> 1, wn = w & 1;
    f32x4 qac[2][2] = {};
    const int scol = ((lane & 7) ^ ((lane >> 3) & 7)) * 8;
    const u16* Ag = xn + (size_t)(b*512 + f0 + w*8 + (lane >> 3)) * 1024 + scol;
    const u16* Bg = Wqt + (size_t)(n*64 + w*8 + (lane >> 3)) * 1024 + scol;
    const int dq = w * 512;

#define STAGEQ(buf, k0)                                         \
    gload16(Ag + (k0),            Als + (buf)*4096 + dq);       \
    gload16(Ag + 32*1024 + (k0),  Als + (buf)*4096 + dq + 2048);\
    gload16(Bg + (k0),            Bls + (buf)*4096 + dq);       \
    gload16(Bg + 32*1024 + (k0),  Bls + (buf)*4096 + dq + 2048);

    STAGEQ(0, 0);
    __syncthreads();
    for (int t = 0; t < 16; t++){
      const int cur = t & 1;
      if (t < 15){ STAGEQ(cur ^ 1, (t + 1) << 6); }
      const u16* Ab = Als + cur * 4096;
      const u16* Bb = Bls + cur * 4096;
#pragma unroll
      for (int ks = 0; ks < 2; ks++){
        const int sl = (((ks << 2) + g) ^ e7) << 3;
        u16x8 av[2], bv[2];
#pragma unroll
        for (int mi = 0; mi < 2; mi++)
          av[mi] = *(const u16x8*)(Ab + (wm*32 + mi*16 + l15) * 64 + sl);
#pragma unroll
        for (int ni = 0; ni < 2; ni++)
          bv[ni] = *(const u16x8*)(Bb + (wn*32 + ni*16 + l15) * 64 + sl);
#pragma unroll
        for (int mi = 0; mi < 2; mi++)
#pragma unroll
          for (int ni = 0; ni < 2; ni++)
            qac[mi][ni] = MFMA16(av[mi], bv[ni], qac[mi][ni]);
      }
      __syncthreads();
    }
#undef STAGEQ

    u16* Qt = &Pl[2][0];
#pragma unroll
    for (int mi = 0; mi < 2; mi++)
#pragma unroll
      for (int ni = 0; ni < 2; ni++)
#pragma unroll
        for (int j = 0; j < 4; j++){
          const int r = wm*32 + mi*16 + g*4 + j;
          const int c = wn*32 + ni*16 + l15;
          const int byte = r*128 + (((c >> 3) ^ (r & 7)) << 4) + (c & 7)*2;
          *(u16*)((char*)Qt + byte) = f2bf(qac[mi][ni][j] * 0.125f);
        }
    __syncthreads();
    const int r = w*16 + l15;
    const char* qrow = (char*)Qt + r*128;
    qf0 = *(const u16x8*)(qrow + ((g ^ (r & 7)) << 4));
    qf1 = *(const u16x8*)(qrow + (((4 + g) ^ (r & 7)) << 4));
    __syncthreads();
  }

  // QK^T: acc[tf] holds S[fw+l15][tf*16 + g*4 + j]
  f32x4 acc[32];
  const u16* kp = Kb + ((size_t)b*512 + l15) * 1024 + n*64 + g*8;
#pragma unroll
  for (int tf = 0; tf < 32; tf++){
    u16x8 k0 = *(const u16x8*)(kp + (size_t)tf*16*1024);
    u16x8 k1 = *(const u16x8*)(kp + (size_t)tf*16*1024 + 32);
    f32x4 z = {0.f, 0.f, 0.f, 0.f};
    z = MFMA16(k0, qf0, z);
    acc[tf] = MFMA16(k1, qf1, z);
  }

  // + qs bias (bf16) + attn bias, row max
  const u16* qsp = qs + ((size_t)b*512 + fw + l15) * 512 + g*4;
  const float* abp = abias + (size_t)b*512 + g*4;
  float m = -3.0e38f;
#pragma unroll
  for (int tf = 0; tf < 32; tf++){
    u16x4 qv = *(const u16x4*)(qsp + tf*16);
    float4 av = *(const float4*)(abp + tf*16);
    acc[tf][0] += bf2f(qv[0]) + av.x;
    acc[tf][1] += bf2f(qv[1]) + av.y;
    acc[tf][2] += bf2f(qv[2]) + av.z;
    acc[tf][3] += bf2f(qv[3]) + av.w;
    m = fmaxf(m, fmaxf(fmaxf(acc[tf][0], acc[tf][1]), fmaxf(acc[tf][2], acc[tf][3])));
  }
  m = fmaxf(m, __shfl_xor(m, 16, 64));
  m = fmaxf(m, __shfl_xor(m, 32, 64));

  float s = 0.f;
#pragma unroll
  for (int tf = 0; tf < 32; tf++){
#pragma unroll
    for (int j = 0; j < 4; j++){
      float e = __expf(acc[tf][j] - m);
      acc[tf][j] = e; s += e;
    }
  }
  s += __shfl_xor(s, 16, 64);
  s += __shfl_xor(s, 32, 64);
  const float inv = 1.0f / s;
  float invj[4];
#pragma unroll
  for (int j = 0; j < 4; j++) invj[j] = __shfl(inv, g*4 + j, 64);

  // store unnormalized P (<=1) row-major [16][512] bf16, chunk-swizzled
#pragma unroll
  for (int tf = 0; tf < 32; tf++){
    const int chunk = tf*2 + (g >> 1);
    const int boff = (l15 << 10) + ((chunk ^ e7) << 4) + ((g & 1) << 3);
    u16x4 pk = { f2bf(acc[tf][0]), f2bf(acc[tf][1]), f2bf(acc[tf][2]), f2bf(acc[tf][3]) };
    *(u16x4*)((char*)pw + boff) = pk;
  }

  // PV: O[f][h] = P[f][:] @ V[:][h];  V^T frags direct from global (L2-resident)
  f32x4 oacc[4] = {};
  const u16* vp = Vt + ((size_t)(b*16 + n)*64 + l15) * 512 + g*8;
  for (int kk = 0; kk < 16; kk++){
    u16x8 pa = *(const u16x8*)((char*)pw + (l15 << 10) + ((((kk << 2) + g) ^ e7) << 4));
#pragma unroll
    for (int nf = 0; nf < 4; nf++){
      u16x8 vb = *(const u16x8*)(vp + (size_t)nf*16*512 + kk*32);
      oacc[nf] = MFMA16(pa, vb, oacc[nf]);
    }
  }

  u16* op = aout + ((size_t)b*512 + fw + g*4) * 1024 + n*64 + l15;
#pragma unroll
  for (int nf = 0; nf < 4; nf++)
#pragma unroll
    for (int j = 0; j < 4; j++)
      op[(size_t)j*1024 + nf*16] = f2bf(oacc[nf][j] * invj[j]);
}

// ---------------- host ----------------
extern "C" void kernel_launch(void* const* d_in, const int* in_sizes, int n_in,
                              void* d_out, int out_size, void* d_ws, size_t ws_size,
                              hipStream_t stream){
  const float* dec_in   = (const float*)d_in[0];
  const float* enc      = (const float*)d_in[1];
  const float* dist     = (const float*)d_in[3];
  const float* abias    = (const float*)d_in[5];
  const float* Wq  = (const float*)d_in[6];
  const float* Wk  = (const float*)d_in[7];
  const float* Wv  = (const float*)d_in[8];
  const float* Wo  = (const float*)d_in[9];
  const float* Wth = (const float*)d_in[10];
  const float* bth = (const float*)d_in[11];
  const float* Wto = (const float*)d_in[12];
  const float* bto = (const float*)d_in[13];
  const float* Wf1 = (const float*)d_in[14];
  const float* bf1 = (const float*)d_in[15];
  const float* Wf2 = (const float*)d_in[16];
  const float* bf2 = (const float*)d_in[17];
  float* dout = (float*)d_out;

  char* wp = (char*)d_ws;
  auto alloc = [&](size_t n) -> char* {
    char* p = wp; wp += (n + 255) & ~(size_t)255; return p;
  };
  float* x     = (float*)alloc((size_t)1048576 * 4);
  u16*  xn     = (u16*)alloc((size_t)1048576 * 2);
  u16*  encb   = (u16*)alloc((size_t)1048576 * 2);
  u16*  Wqt    = (u16*)alloc((size_t)4194304 * 2);    // 4 layers
  u16*  Wkt    = (u16*)alloc((size_t)4194304 * 2);
  u16*  Wvt    = (u16*)alloc((size_t)4194304 * 2);
  u16*  Wot    = (u16*)alloc((size_t)4194304 * 2);
  u16*  Wf1t   = (u16*)alloc((size_t)16777216 * 2);   // 4 layers
  u16*  Wf2t   = (u16*)alloc((size_t)16777216 * 2);
  u16*  Kb     = (u16*)alloc((size_t)4194304 * 2);    // 4 layers
  u16*  Vt     = (u16*)alloc((size_t)4194304 * 2);
  u16*  qs     = (u16*)alloc((size_t)2097152 * 2);    // 4 layers, bf16
  u16*  aout   = (u16*)alloc((size_t)1048576 * 2);
  u16*  ffh    = (u16*)alloc((size_t)4194304 * 2);
  float* part  = (float*)alloc((size_t)4194304 * 4);  // 4x 1024x1024 f32

  // ---- upfront (2 dispatches) ----
  // prep_A: only what gemmKV needs (Wk/Wv transposes, enc) + LN of dec_in
  prepA_k<<<2560, 256, 0, stream>>>(Wk, Wv, enc, dec_in, x, xn, Wkt, Wvt, encb);
  // prep_B (Wq/Wf1/Wf2 transposes + qs) co-dispatched with gemmKV
  prepB_gemmKV_k<<<5376, 256, 0, stream>>>(Wq, Wf1, Wf2, dist, Wth, bth, Wto, bto,
                                           encb, Wkt, Wvt,
                                           Wqt, Wf1t, Wf2t, qs, Kb, Vt);

  // Wo transpose folded into the first layer's attn window?  No — keep Wot
  // produced upfront by reusing trans4 blocks inside prepB (Wq region covers
  // only Wq).  Wot is needed at layer 0's O-proj: transpose it in prepA's
  // spare capacity would serialize; instead it rides in prepB?  It does not —
  // Wot is consumed AFTER attn layer 0, well past dispatch 2.  Add it to
  // prep_B's transpose regions in a later round if profitable.
  // For now Wot is transposed here (small, 4 mats):
  // (reuses prepA_k layout: sel 0/1 -> two weight arrays)
  prepA_k<<<512, 256, 0, stream>>>(Wo, Wo, nullptr, nullptr, nullptr, nullptr,
                                   Wot, Wot, nullptr);

  // ---- per-layer serial chain: 6 dispatches ----
  for (int i = 0; i < 4; i++){
    const size_t wo = (size_t)i * 1048576;

    // fused attention (Q-proj + logits + biases + softmax + PV)
    attn_k<<<dim3(16, 8, 2), 256, 0, stream>>>(xn, Wqt + wo, Kb + wo, Vt + wo,
                                               qs + (size_t)i * 524288, abias, aout);

    // O projection (split-K=4) + fused residual+LN
    gemm_splitk_k<<<dim3(16, 8, 4), 256, 0, stream>>>(aout, 1024, Wot + wo, 1024, 256, part);
    reduce_ln_k<0, 0><<<1024, 256, 0, stream>>>(part, nullptr, x, xn, nullptr);

    // FFN
    gemm128_k<3><<<dim3(64, 8), 256, 0, stream>>>(xn, 1024, Wf1t + (size_t)i*4194304, 1024,
                                                  1024, 4096, ffh, bf1 + (size_t)i*4096);
    gemm_splitk_k<<<dim3(16, 8, 4), 256, 0, stream>>>(ffh, 4096, Wf2t + (size_t)i*4194304, 4096,
                                                      1024, part);
    if (i < 3)
      reduce_ln_k<1, 0><<<1024, 256, 0, stream>>>(part, bf2 + (size_t)i*1024, x, xn, nullptr);
    else
      reduce_ln_k<1, 1><<<1024, 256, 0, stream>>>(part, bf2 + (size_t)i*1024, x, nullptr, dout);
  }
}